// Round 18
// baseline (185.685 us; speedup 1.0000x reference)
//
#include <hip/hip_runtime.h>
#include <hip/hip_bf16.h>
#include <float.h>

// Problem constants
#define Bz   4
#define Nn   384
#define Dd   256
#define Hh   4
#define DHh  64
#define NSQ  (384*384)
#define NEG_MAX (-3.40282346638528859812e+38f)

typedef __attribute__((ext_vector_type(8))) short short8;
typedef __attribute__((ext_vector_type(4))) float f32x4;
typedef unsigned short ushort_t;

// fast exact-gelu: erf via Abramowitz-Stegun 7.1.26 (|err| <= 1.5e-7)
__device__ __forceinline__ float gelu_f(float x){
  const float y = __builtin_fabsf(x) * 0.70710678118654752f;
  const float t = __builtin_amdgcn_rcpf(fmaf(0.3275911f, y, 1.0f));
  float poly = fmaf(1.061405429f, t, -1.453152027f);
  poly = fmaf(poly, t, 1.421413741f);
  poly = fmaf(poly, t, -0.284496736f);
  poly = fmaf(poly, t, 0.254829592f);
  poly *= t;
  const float e = __expf(-y * y);
  const float erfa = fmaf(-poly, e, 1.0f);
  const float er = __builtin_copysignf(erfa, x);
  return 0.5f * x * (1.0f + er);
}
__device__ __forceinline__ float wsum(float v){
  #pragma unroll
  for (int o = 32; o > 0; o >>= 1) v += __shfl_xor(v, o, 64);
  return v;
}
__device__ __forceinline__ float4 ld4(const float* p){ return *(const float4*)p; }
__device__ __forceinline__ f32x4 ldv4(const float* p){ return *(const f32x4*)p; }

// fp32 <-> bf16
__device__ __forceinline__ ushort_t f2bfu(float f){
  union { float f; unsigned u; } v; v.f = f;
  unsigned r = v.u + 0x7FFFu + ((v.u >> 16) & 1u);
  return (ushort_t)(r >> 16);
}
__device__ __forceinline__ short f2bf(float f){ return (short)f2bfu(f); }
__device__ __forceinline__ float bfe2f(ushort_t u){
  union { unsigned u; float f; } v; v.u = ((unsigned)u) << 16; return v.f;
}
__device__ __forceinline__ void addbf(f32x4& a, f32x4& b, short8 v){
  a[0] += bfe2f((ushort_t)v[0]); a[1] += bfe2f((ushort_t)v[1]);
  a[2] += bfe2f((ushort_t)v[2]); a[3] += bfe2f((ushort_t)v[3]);
  b[0] += bfe2f((ushort_t)v[4]); b[1] += bfe2f((ushort_t)v[5]);
  b[2] += bfe2f((ushort_t)v[6]); b[3] += bfe2f((ushort_t)v[7]);
}

// ---------------------------------------------------------------------------
// prep (merged with pack): permuted bf16 tables, w1bf/w2bf, bf16 weights,
// and per-pair 16B records contP.
// ---------------------------------------------------------------------------
__global__ __launch_bounds__(256) void prep_kernel(
    const int* __restrict__ dgk, const int* __restrict__ ctk,
    const float* __restrict__ Edg, const float* __restrict__ Ec,
    const float* __restrict__ b2,
    const float* __restrict__ W1, const float* __restrict__ b1,
    const float* __restrict__ W2,
    const float* __restrict__ Ed, const float* __restrict__ Edi,
    const float* __restrict__ Er, const float* __restrict__ Eh,
    const float* __restrict__ Ee, const float* __restrict__ Esp,
    const float* __restrict__ Es,
    const float* __restrict__ Wq, const float* __restrict__ Wk,
    const float* __restrict__ Wv, const float* __restrict__ Wo,
    const float* __restrict__ ffW1, const float* __restrict__ ffW2,
    const int* __restrict__ dbk, const int* __restrict__ drk,
    const int* __restrict__ rpk, const int* __restrict__ hdk,
    const int* __restrict__ etk, const int* __restrict__ spk,
    const int* __restrict__ sck, const int* __restrict__ pm,
    const float* __restrict__ cont,
    ushort_t* __restrict__ dcP, ushort_t* __restrict__ dcbP,
    ushort_t* __restrict__ w1bf, ushort_t* __restrict__ w2bf,
    ushort_t* __restrict__ EddP, ushort_t* __restrict__ ErsP,
    ushort_t* __restrict__ EhesP,
    ushort_t* __restrict__ wqB, ushort_t* __restrict__ wkB,
    ushort_t* __restrict__ wvB, ushort_t* __restrict__ woB,
    ushort_t* __restrict__ ffW1B, ushort_t* __restrict__ ffW2B,
    ushort_t* __restrict__ contP)
{
  const int idx = blockIdx.x * 256 + threadIdx.x;
  if (idx < 24576) {                       // dcP / dcbP (permuted bf16)
    const int row = idx >> 4;
    const int q   = (idx & 15) << 2;
    const int pos = ((q >> 2) & 3) * 16 + (q >> 4) * 4;
    const float4 a = ld4(Edg + (dgk[row] << 6) + q);
    const float4 b = ld4(Ec  + (ctk[row] << 6) + q);
    const float4 bb4 = ld4(b2 + q);
    ushort4 o, o2;
    o.x = f2bfu(a.x + b.x); o.y = f2bfu(a.y + b.y);
    o.z = f2bfu(a.z + b.z); o.w = f2bfu(a.w + b.w);
    o2.x = f2bfu(a.x + b.x + bb4.x); o2.y = f2bfu(a.y + b.y + bb4.y);
    o2.z = f2bfu(a.z + b.z + bb4.z); o2.w = f2bfu(a.w + b.w + bb4.w);
    *(ushort4*)(dcP  + row * 64 + pos) = o;
    *(ushort4*)(dcbP + row * 64 + pos) = o2;
  } else if (idx < 26624) {                // w2bf [c][k]
    const int t = idx - 24576;
    const int c = t >> 5, k2 = (t & 31) << 1;
    w2bf[c * 64 + k2]     = f2bfu(W2[c * 64 + k2]);
    w2bf[c * 64 + k2 + 1] = f2bfu(W2[c * 64 + k2 + 1]);
  } else if (idx < 26688) {                // w1bf {W1 row, b1, 0} bf16
    const int k = idx - 26624;
    #pragma unroll
    for (int d = 0; d < 6; ++d) w1bf[k * 8 + d] = f2bfu(W1[k * 6 + d]);
    w1bf[k * 8 + 6] = f2bfu(b1[k]);
    w1bf[k * 8 + 7] = 0;
  } else if (idx < 28128) {                // EddP: 90 rows, permuted bf16
    const int t = idx - 26688;
    const int row = t >> 4, q = (t & 15) << 2;
    const int pos = ((q >> 2) & 3) * 16 + (q >> 4) * 4;
    const int d = row / 10, r = row - d * 10;
    const float4 a = ld4(Ed + (d << 6) + q);
    const float4 b = ld4(Edi + (r << 6) + q);
    ushort4 o;
    o.x = f2bfu(a.x + b.x); o.y = f2bfu(a.y + b.y);
    o.z = f2bfu(a.z + b.z); o.w = f2bfu(a.w + b.w);
    *(ushort4*)(EddP + row * 64 + pos) = o;
  } else if (idx < 29088) {                // ErsP: 60 rows
    const int t = idx - 28128;
    const int row = t >> 4, q = (t & 15) << 2;
    const int pos = ((q >> 2) & 3) * 16 + (q >> 4) * 4;
    const int ro = row / 6, s = row - ro * 6;
    const float4 a = ld4(Er + (ro << 6) + q);
    const float4 b = ld4(Esp + (s << 6) + q);
    ushort4 o;
    o.x = f2bfu(a.x + b.x); o.y = f2bfu(a.y + b.y);
    o.z = f2bfu(a.z + b.z); o.w = f2bfu(a.w + b.w);
    *(ushort4*)(ErsP + row * 64 + pos) = o;
  } else if (idx < 30048) {                // EhesP: 60 rows
    const int t = idx - 29088;
    const int row = t >> 4, q = (t & 15) << 2;
    const int pos = ((q >> 2) & 3) * 16 + (q >> 4) * 4;
    const int h = row / 15, rem = row - h * 15;
    const int e = rem / 3, sm = rem - e * 3;
    const float4 a = ld4(Eh + (h << 6) + q);
    const float4 b = ld4(Ee + (e << 6) + q);
    const float4 c = ld4(Es + (sm << 6) + q);
    ushort4 o;
    o.x = f2bfu(a.x + b.x + c.x); o.y = f2bfu(a.y + b.y + c.y);
    o.z = f2bfu(a.z + b.z + c.z); o.w = f2bfu(a.w + b.w + c.w);
    *(ushort4*)(EhesP + row * 64 + pos) = o;
  } else if (idx < 193888) {               // weight bf16 packs, 4 elems/thread
    const int t = idx - 30048;
    const float* src; ushort_t* dst; int e;
    if (t < 16384)      { src = Wq;   dst = wqB;   e = t << 2; }
    else if (t < 32768) { src = Wk;   dst = wkB;   e = (t - 16384) << 2; }
    else if (t < 49152) { src = Wv;   dst = wvB;   e = (t - 32768) << 2; }
    else if (t < 65536) { src = Wo;   dst = woB;   e = (t - 49152) << 2; }
    else if (t < 131072){ src = ffW1; dst = ffW1B; e = (t - 65536) << 2; }
    else                { src = ffW2; dst = ffW2B; e = (t - 131072) << 2; }
    const float4 v = ld4(src + e);
    ushort4 o;
    o.x = f2bfu(v.x); o.y = f2bfu(v.y); o.z = f2bfu(v.z); o.w = f2bfu(v.w);
    *(ushort4*)(dst + e) = o;
  } else if (idx < 193888 + Bz * Nn * Nn) { // pack: per-pair 16B record
    const int p = idx - 193888;
    const float* cp = cont + (size_t)p * 6;
    short8 r;
    r[0] = f2bf(cp[0]); r[1] = f2bf(cp[1]); r[2] = f2bf(cp[2]);
    r[3] = f2bf(cp[3]); r[4] = f2bf(cp[4]); r[5] = f2bf(cp[5]);
    const unsigned iv = (unsigned)(dbk[p] * 10 + drk[p])
                      | ((unsigned)(rpk[p] * 6 + spk[p]) << 7)
                      | ((unsigned)((hdk[p] * 5 + etk[p]) * 3 + sck[p]) << 13)
                      | ((pm[p] ? 1u : 0u) << 19);
    r[6] = (short)(iv & 0xffffu);
    r[7] = (short)(iv >> 16);
    *(short8*)(contP + (size_t)p * 8) = r;
  }
}

// ---------------------------------------------------------------------------
// Fused pair kernel v14: 2 tiles/wave (32 pairs); peak pressure ~110-120 regs
// fits the 128-reg cap of 4 waves/SIMD.  Spill tell: WRITE_SIZE >> 9.2 MB.
// ---------------------------------------------------------------------------
__global__ __launch_bounds__(256, 4) void pair_kernel(
    const ushort_t* __restrict__ contP,
    const ushort_t* __restrict__ w1bf, const ushort_t* __restrict__ w2bf,
    const ushort_t* __restrict__ EddP, const ushort_t* __restrict__ ErsP,
    const ushort_t* __restrict__ EhesP,
    const float* __restrict__ lng, const float* __restrict__ lnb,
    const float* __restrict__ bW, const float* __restrict__ bb,
    const ushort_t* __restrict__ dcP, const ushort_t* __restrict__ dcbP,
    float* __restrict__ biasOut)
{
  const int tid  = threadIdx.x;
  const int lane = tid & 63;
  const int l15  = lane & 15, lg = lane >> 4;
  const int wid  = blockIdx.x * 4 + (tid >> 6);               // [0, 18432)
  const int rowU = __builtin_amdgcn_readfirstlane(wid / 12);  // b*N+i
  const int jb   = wid - rowU * 12;
  const int b    = rowU / Nn;
  const int i    = rowU - b * Nn;
  const int j0   = jb * 32 + l15;
  const size_t pbase = (size_t)rowU * Nn + j0;
  const int colOff = lg << 2;

  const short8 rec0 = *(const short8*)(contP + (pbase + 0) * 8);
  const short8 rec1 = *(const short8*)(contP + (pbase + 16) * 8);
  asm volatile("" :: "v"(rec0), "v"(rec1));
  const unsigned ix0 = (unsigned)(ushort_t)rec0[6] | ((unsigned)(ushort_t)rec0[7] << 16);
  const unsigned ix1 = (unsigned)(ushort_t)rec1[6] | ((unsigned)(ushort_t)rec1[7] << 16);
  const float c00 = bfe2f((ushort_t)rec0[0]), c01 = bfe2f((ushort_t)rec0[1]),
              c02 = bfe2f((ushort_t)rec0[2]), c03 = bfe2f((ushort_t)rec0[3]),
              c04 = bfe2f((ushort_t)rec0[4]), c05 = bfe2f((ushort_t)rec0[5]);
  const float c10 = bfe2f((ushort_t)rec1[0]), c11 = bfe2f((ushort_t)rec1[1]),
              c12 = bfe2f((ushort_t)rec1[2]), c13 = bfe2f((ushort_t)rec1[3]),
              c14 = bfe2f((ushort_t)rec1[4]), c15 = bfe2f((ushort_t)rec1[5]);

  short8 b0a, b0b, b1a, b1b;
#define H1ROW(R, JJ, D0, D1) { \
    const float w0 = bfe2f((ushort_t)R[0]), w1 = bfe2f((ushort_t)R[1]), \
                w2 = bfe2f((ushort_t)R[2]), w3 = bfe2f((ushort_t)R[3]), \
                w4 = bfe2f((ushort_t)R[4]), w5 = bfe2f((ushort_t)R[5]), \
                w6 = bfe2f((ushort_t)R[6]); \
    float s0 = w6, s1 = w6; \
    s0 = fmaf(w0, c00, s0); s0 = fmaf(w1, c01, s0); s0 = fmaf(w2, c02, s0); \
    s0 = fmaf(w3, c03, s0); s0 = fmaf(w4, c04, s0); s0 = fmaf(w5, c05, s0); \
    s1 = fmaf(w0, c10, s1); s1 = fmaf(w1, c11, s1); s1 = fmaf(w2, c12, s1); \
    s1 = fmaf(w3, c13, s1); s1 = fmaf(w4, c14, s1); s1 = fmaf(w5, c15, s1); \
    D0[JJ] = f2bf(gelu_f(s0)); D1[JJ] = f2bf(gelu_f(s1)); }
  {
    const ushort_t* wb_ = w1bf + ((lg << 3) << 3);
    const short8 r0 = *(const short8*)(wb_ +  0);
    const short8 r1 = *(const short8*)(wb_ +  8);
    const short8 r2 = *(const short8*)(wb_ + 16);
    const short8 r3 = *(const short8*)(wb_ + 24);
    const short8 r4 = *(const short8*)(wb_ + 32);
    const short8 r5 = *(const short8*)(wb_ + 40);
    const short8 r6 = *(const short8*)(wb_ + 48);
    const short8 r7 = *(const short8*)(wb_ + 56);
    asm volatile("" :: "v"(r0), "v"(r1), "v"(r2), "v"(r3),
                       "v"(r4), "v"(r5), "v"(r6), "v"(r7));
    H1ROW(r0, 0, b0a, b1a) H1ROW(r1, 1, b0a, b1a)
    H1ROW(r2, 2, b0a, b1a) H1ROW(r3, 3, b0a, b1a)
    H1ROW(r4, 4, b0a, b1a) H1ROW(r5, 5, b0a, b1a)
    H1ROW(r6, 6, b0a, b1a) H1ROW(r7, 7, b0a, b1a)
  }
  {
    const ushort_t* wb_ = w1bf + ((32 + (lg << 3)) << 3);
    const short8 r0 = *(const short8*)(wb_ +  0);
    const short8 r1 = *(const short8*)(wb_ +  8);
    const short8 r2 = *(const short8*)(wb_ + 16);
    const short8 r3 = *(const short8*)(wb_ + 24);
    const short8 r4 = *(const short8*)(wb_ + 32);
    const short8 r5 = *(const short8*)(wb_ + 40);
    const short8 r6 = *(const short8*)(wb_ + 48);
    const short8 r7 = *(const short8*)(wb_ + 56);
    asm volatile("" :: "v"(r0), "v"(r1), "v"(r2), "v"(r3),
                       "v"(r4), "v"(r5), "v"(r6), "v"(r7));
    H1ROW(r0, 0, b0b, b1b) H1ROW(r1, 1, b0b, b1b)
    H1ROW(r2, 2, b0b, b1b) H1ROW(r3, 3, b0b, b1b)
    H1ROW(r4, 4, b0b, b1b) H1ROW(r5, 5, b0b, b1b)
    H1ROW(r6, 6, b0b, b1b) H1ROW(r7, 7, b0b, b1b)
  }
#undef H1ROW

  const ushort_t* wbase = w2bf + (size_t)l15 * 64 + (lg << 3);
  const short8 wa0 = *(const short8*)(wbase);
  const short8 wc0 = *(const short8*)(wbase + 32);
  const short8 wa1 = *(const short8*)(wbase + 16 * 64);
  const short8 wc1 = *(const short8*)(wbase + 16 * 64 + 32);
  const short8 wa2 = *(const short8*)(wbase + 32 * 64);
  const short8 wc2 = *(const short8*)(wbase + 32 * 64 + 32);
  const short8 wa3 = *(const short8*)(wbase + 48 * 64);
  const short8 wc3 = *(const short8*)(wbase + 48 * 64 + 32);
  asm volatile("" :: "v"(wa0), "v"(wc0), "v"(wa1), "v"(wc1),
                     "v"(wa2), "v"(wc2), "v"(wa3), "v"(wc3));
  f32x4 acc0[4] = {}, acc1[4] = {};
#define MM(ACC, BA, BB) \
  ACC[0] = __builtin_amdgcn_mfma_f32_16x16x32_bf16(wa0, BA, ACC[0], 0, 0, 0); \
  ACC[0] = __builtin_amdgcn_mfma_f32_16x16x32_bf16(wc0, BB, ACC[0], 0, 0, 0); \
  ACC[1] = __builtin_amdgcn_mfma_f32_16x16x32_bf16(wa1, BA, ACC[1], 0, 0, 0); \
  ACC[1] = __builtin_amdgcn_mfma_f32_16x16x32_bf16(wc1, BB, ACC[1], 0, 0, 0); \
  ACC[2] = __builtin_amdgcn_mfma_f32_16x16x32_bf16(wa2, BA, ACC[2], 0, 0, 0); \
  ACC[2] = __builtin_amdgcn_mfma_f32_16x16x32_bf16(wc2, BB, ACC[2], 0, 0, 0); \
  ACC[3] = __builtin_amdgcn_mfma_f32_16x16x32_bf16(wa3, BA, ACC[3], 0, 0, 0); \
  ACC[3] = __builtin_amdgcn_mfma_f32_16x16x32_bf16(wc3, BB, ACC[3], 0, 0, 0);
  MM(acc0, b0a, b0b) MM(acc1, b1a, b1b)
#undef MM

#define GATHER(ACC, IX, JOFF) { \
    const int xdd  = ((IX) & 127) << 6; \
    const int xrs  = (((IX) >> 7) & 63) << 6; \
    const int xhes = (((IX) >> 13) & 63) << 6; \
    const ushort_t* ep = EddP  + xdd  + (lg << 4); \
    const ushort_t* rp = ErsP  + xrs  + (lg << 4); \
    const ushort_t* hp = EhesP + xhes + (lg << 4); \
    const ushort_t* jp = dcP + (((size_t)(b * Nn + j0 + (JOFF))) << 6) + (lg << 4); \
    const short8 e0 = *(const short8*)ep,       e1 = *(const short8*)(ep + 8); \
    const short8 r0 = *(const short8*)rp,       r1 = *(const short8*)(rp + 8); \
    const short8 h0 = *(const short8*)hp,       h1 = *(const short8*)(hp + 8); \
    const short8 jv0 = *(const short8*)jp,      jv1 = *(const short8*)(jp + 8); \
    asm volatile("" :: "v"(e0), "v"(e1), "v"(r0), "v"(r1), \
                       "v"(h0), "v"(h1), "v"(jv0), "v"(jv1)); \
    addbf(ACC[0], ACC[1], e0);  addbf(ACC[2], ACC[3], e1); \
    addbf(ACC[0], ACC[1], r0);  addbf(ACC[2], ACC[3], r1); \
    addbf(ACC[0], ACC[1], h0);  addbf(ACC[2], ACC[3], h1); \
    addbf(ACC[0], ACC[1], jv0); addbf(ACC[2], ACC[3], jv1); }
  GATHER(acc0, ix0, 0)
  GATHER(acc1, ix1, 16)
#undef GATHER
  {
    const ushort_t* up = dcbP + (((size_t)rowU) << 6) + (lg << 4);
    const short8 u0 = *(const short8*)up, u1 = *(const short8*)(up + 8);
    f32x4 du0, du1, du2, du3;
    #pragma unroll
    for (int r = 0; r < 4; ++r) {
      du0[r] = bfe2f((ushort_t)u0[r]);     du1[r] = bfe2f((ushort_t)u0[4 + r]);
      du2[r] = bfe2f((ushort_t)u1[r]);     du3[r] = bfe2f((ushort_t)u1[4 + r]);
    }
    acc0[0] += du0; acc0[1] += du1; acc0[2] += du2; acc0[3] += du3;
    acc1[0] += du0; acc1[1] += du1; acc1[2] += du2; acc1[3] += du3;
  }

  float mean0, inv0, mean1, inv1;
#define STATS(ACC, MEAN, INV) { \
    float sum = 0.f, sq = 0.f; \
    _Pragma("unroll") \
    for (int mt = 0; mt < 4; ++mt) \
      _Pragma("unroll") \
      for (int r = 0; r < 4; ++r) { \
        const float v = ACC[mt][r]; sum += v; sq = fmaf(v, v, sq); } \
    sum += __shfl_xor(sum, 16, 64); sum += __shfl_xor(sum, 32, 64); \
    sq  += __shfl_xor(sq,  16, 64); sq  += __shfl_xor(sq,  32, 64); \
    MEAN = sum * (1.f / 64.f); \
    INV  = rsqrtf(sq * (1.f / 64.f) - MEAN * MEAN + 1e-5f); }
  STATS(acc0, mean0, inv0) STATS(acc1, mean1, inv1)
#undef STATS

  float h00 = 0.f, h01 = 0.f, h02 = 0.f, h03 = 0.f;
  float h10 = 0.f, h11 = 0.f, h12 = 0.f, h13 = 0.f;
  #pragma unroll
  for (int mt = 0; mt < 4; ++mt) {
    const int c0i = (mt << 4) + colOff;
    const f32x4 g4 = ldv4(lng + c0i);
    const f32x4 b4 = ldv4(lnb + c0i);
    const f32x4 w0 = ldv4(bW + c0i);
    const f32x4 w1_ = ldv4(bW + 64 + c0i);
    const f32x4 w2_ = ldv4(bW + 128 + c0i);
    const f32x4 w3_ = ldv4(bW + 192 + c0i);
    asm volatile("" :: "v"(g4), "v"(b4), "v"(w0), "v"(w1_), "v"(w2_), "v"(w3_));
    #pragma unroll
    for (int r = 0; r < 4; ++r) {
      float g;
      g = gelu_f((acc0[mt][r] - mean0) * inv0 * g4[r] + b4[r]);
      h00 = fmaf(w0[r], g, h00); h01 = fmaf(w1_[r], g, h01);
      h02 = fmaf(w2_[r], g, h02); h03 = fmaf(w3_[r], g, h03);
      g = gelu_f((acc1[mt][r] - mean1) * inv1 * g4[r] + b4[r]);
      h10 = fmaf(w0[r], g, h10); h11 = fmaf(w1_[r], g, h11);
      h12 = fmaf(w2_[r], g, h12); h13 = fmaf(w3_[r], g, h13);
    }
  }
#define RED(H) H += __shfl_xor(H, 16, 64); H += __shfl_xor(H, 32, 64);
  RED(h00) RED(h01) RED(h02) RED(h03)
  RED(h10) RED(h11) RED(h12) RED(h13)
#undef RED

  const float bbl = bb[lg];
  const float bh0 = ((lg == 0) ? h00 : (lg == 1) ? h01 : (lg == 2) ? h02 : h03) + bbl;
  const float bh1 = ((lg == 0) ? h10 : (lg == 1) ? h11 : (lg == 2) ? h12 : h13) + bbl;
  const size_t base = (size_t)b * (Hh * NSQ) + (size_t)lg * NSQ + (size_t)i * Nn;
  biasOut[base + j0]      = bh0 * (((ix0 >> 19) & 1) ? 1.f : 0.f);
  biasOut[base + j0 + 16] = bh1 * (((ix1 >> 19) & 1) ? 1.f : 0.f);
}

// ---------------------------------------------------------------------------
// LayerNorm over last dim (256), bf16 output. One wave per row.
// ---------------------------------------------------------------------------
__global__ __launch_bounds__(256) void ln_kernel(
    const float* __restrict__ x, const float* __restrict__ g,
    const float* __restrict__ bta, ushort_t* __restrict__ o)
{
  const int row  = blockIdx.x * 4 + (threadIdx.x >> 6);
  const int lane = threadIdx.x & 63;
  const float4 v = *(const float4*)(x + (size_t)row * Dd + lane * 4);
  float s = v.x + v.y + v.z + v.w;
  s = wsum(s);
  const float m = s * (1.f / 256.f);
  const float dx = v.x - m, dy = v.y - m, dz = v.z - m, dw = v.w - m;
  float q = dx*dx + dy*dy + dz*dz + dw*dw;
  q = wsum(q);
  const float inv = rsqrtf(q * (1.f / 256.f) + 1e-5f);
  const int d = lane * 4;
  const float4 gg = *(const float4*)(g + d);
  const float4 bb = *(const float4*)(bta + d);
  ushort4 out;
  out.x = f2bfu(dx * inv * gg.x + bb.x);
  out.y = f2bfu(dy * inv * gg.y + bb.y);
  out.z = f2bfu(dz * inv * gg.z + bb.z);
  out.w = f2bfu(dw * inv * gg.w + bb.w);
  *(ushort4*)(o + (size_t)row * Dd + d) = out;
}

// ---------------------------------------------------------------------------
// Fused QKV: all-bf16 fragments. z: {wqB->qbB, wkB->kbB, wvB->vbT}.
// ---------------------------------------------------------------------------
__global__ __launch_bounds__(256) void qkv_kernel(
    const ushort_t* __restrict__ xnb,
    const ushort_t* __restrict__ wqB, const ushort_t* __restrict__ wkB,
    const ushort_t* __restrict__ wvB,
    ushort_t* __restrict__ qbB, ushort_t* __restrict__ kbB,
    ushort_t* __restrict__ vbT)
{
  const int tid = threadIdx.x;
  const int lane = tid & 63;
  const int w   = tid >> 6;
  const int l15 = lane & 15, lg = lane >> 4;
  const int m0 = blockIdx.y * 64 + w * 16;
  const int n0 = blockIdx.x * 64;
  const int z  = blockIdx.z;
  const ushort_t* Bb = (z == 0) ? wqB : (z == 1) ? wkB : wvB;

  f32x4 acc[4] = {};
  const ushort_t* pa = xnb + (size_t)(m0 + l15) * Dd + lg * 8;
  for (int k0 = 0; k0 < Dd; k0 += 32) {
    const short8 af = *(const short8*)(pa + k0);
    #pragma unroll
    for (int nt = 0; nt < 4; ++nt) {
      const short8 bf = *(const short8*)(Bb +
          (size_t)(n0 + nt * 16 + l15) * Dd + k0 + lg * 8);
      acc[nt] = __builtin_amdgcn_mfma_f32_16x16x32_bf16(af, bf, acc[nt], 0, 0, 0);
    }
  }
  if (z < 2) {
    ushort_t* Cb = (z == 0) ? qbB : kbB;
    #pragma unroll
    for (int nt = 0; nt < 4; ++nt)
      #pragma unroll
      for (int r = 0; r < 4; ++r)
        Cb[(size_t)(m0 + lg * 4 + r) * Dd + n0 + nt * 16 + l15] = f2bfu(acc[nt][r]);
  } else {
    const int m = m0 + (lg << 2);
    const int b = m / Nn, tok = m - b * Nn;
    #pragma unroll
    for (int nt = 0; nt < 4; ++nt) {
      const int n = n0 + nt * 16 + l15;
      const int h = n >> 6, dh = n & 63;
      ushort4 s4;
      s4.x = f2bfu(acc[nt][0]); s4.y = f2bfu(acc[nt][1]);
      s4.z = f2bfu(acc[nt][2]); s4.w = f2bfu(acc[nt][3]);
      *(ushort4*)(vbT + ((size_t)((b * 4 + h) * 64 + dh)) * Nn + tok) = s4;
    }
  }
}

// ---------------------------------------------------------------------------
// Fused attention: QK^T + bias + safe-mask + softmax + pair-mask renorm +
// attn write + PV, one block per (16-row tile, bz). 4 waves; wave w owns
// 96 columns. P staged per-wave in LDS for the PV transpose.
// ---------------------------------------------------------------------------
__global__ __launch_bounds__(256) void attn_kernel(
    const ushort_t* __restrict__ qbB, const ushort_t* __restrict__ kbB,
    const ushort_t* __restrict__ vbT,
    const float* __restrict__ biasO, const int* __restrict__ pm,
    const int* __restrict__ vld,
    float* __restrict__ attn, ushort_t* __restrict__ aoB)
{
  __shared__ float stats[3][4][16];
  __shared__ float part[4][16][64];          // 16 KB
  __shared__ ushort_t pstage[4][16][104];    // 13 KB
  const int tid = threadIdx.x;
  const int lane = tid & 63, w = tid >> 6;
  const int l15 = lane & 15, lg = lane >> 4;
  const int bz = blockIdx.y, b = bz >> 2, h = bz & 3;
  const int m0 = blockIdx.x * 16;
  const int n0 = w * 96;

  // ---- QK^T: 16 x 96 logits per wave ----
  f32x4 acc[6];
  const ushort_t* paq = qbB + ((size_t)(b * Nn + m0 + l15)) * Dd + h * DHh;
  const short8 aq0 = *(const short8*)(paq + lg * 8);
  const short8 aq1 = *(const short8*)(paq + 32 + lg * 8);
  #pragma unroll
  for (int nt = 0; nt < 6; ++nt) {
    const ushort_t* pk = kbB + ((size_t)(b * Nn + n0 + nt * 16 + l15)) * Dd
                       + h * DHh + lg * 8;
    const short8 bk0 = *(const short8*)pk;
    const short8 bk1 = *(const short8*)(pk + 32);
    f32x4 a = {};
    a = __builtin_amdgcn_mfma_f32_16x16x32_bf16(aq0, bk0, a, 0, 0, 0);
    a = __builtin_amdgcn_mfma_f32_16x16x32_bf16(aq1, bk1, a, 0, 0, 0);
    acc[nt] = a;
  }

  // ---- bias + safe mask (in place in acc), pm bits packed ----
  const float* bias_r = biasO + (size_t)bz * NSQ;
  const int* pm_b = pm + (size_t)b * NSQ;
  int vldv[4];
  #pragma unroll
  for (int r = 0; r < 4; ++r) vldv[r] = vld[b * Nn + m0 + lg * 4 + r];
  unsigned pmmask = 0;
  #pragma unroll
  for (int nt = 0; nt < 6; ++nt) {
    #pragma unroll
    for (int r = 0; r < 4; ++r) {
      const int m = m0 + lg * 4 + r;
      const int n = n0 + nt * 16 + l15;
      const size_t off = (size_t)m * Nn + n;
      const float bv = bias_r[off];
      const int q = pm_b[off];
      const bool sf = (q != 0) || (vldv[r] == 0 && m == n);
      if (q) pmmask |= 1u << (nt * 4 + r);
      acc[nt][r] = sf ? fmaf(acc[nt][r], 0.125f, bv) : NEG_MAX;
    }
  }

  // ---- per-row stats over this wave's 96 cols ----
  float mx[4], sr[4], spr[4];
  #pragma unroll
  for (int r = 0; r < 4; ++r) {
    float m_ = NEG_MAX;
    #pragma unroll
    for (int nt = 0; nt < 6; ++nt) m_ = fmaxf(m_, acc[nt][r]);
    #pragma unroll
    for (int o = 1; o <= 8; o <<= 1) m_ = fmaxf(m_, __shfl_xor(m_, o, 64));
    float s_ = 0.f, sp_ = 0.f;
    #pragma unroll
    for (int nt = 0; nt < 6; ++nt) {
      const float e = __expf(acc[nt][r] - m_);
      s_ += e;
      sp_ += ((pmmask >> (nt * 4 + r)) & 1) ? e : 0.f;
    }
    #pragma unroll
    for (int o = 1; o <= 8; o <<= 1) {
      s_ += __shfl_xor(s_, o, 64);
      sp_ += __shfl_xor(sp_, o, 64);
    }
    mx[r] = m_; sr[r] = s_; spr[r] = sp_;
  }
  if (l15 == 0) {
    #pragma unroll
    for (int r = 0; r < 4; ++r) {
      stats[0][w][lg * 4 + r] = mx[r];
      stats[1][w][lg * 4 + r] = sr[r];
      stats[2][w][lg * 4 + r] = spr[r];
    }
  }
  __syncthreads();
  float mr[4], rinv[4];
  #pragma unroll
  for (int r = 0; r < 4; ++r) {
    const int row = lg * 4 + r;
    float M = NEG_MAX, S = 0.f, SP = 0.f;
    #pragma unroll
    for (int wv = 0; wv < 4; ++wv) {
      const float m2 = stats[0][wv][row];
      const float s2 = stats[1][wv][row];
      const float sp2 = stats[2][wv][row];
      const float mn = fmaxf(M, m2);
      const float f1 = __expf(M - mn), f2 = __expf(m2 - mn);
      S = S * f1 + s2 * f2;
      SP = SP * f1 + sp2 * f2;
      M = mn;
    }
    mr[r] = M;
    rinv[r] = 1.f / fmaxf(SP, 1e-6f * S);
  }

  // ---- attn values: write global + stage bf16 P in per-wave LDS ----
  float* attn_b = attn + (size_t)bz * NSQ;
  #pragma unroll
  for (int nt = 0; nt < 6; ++nt) {
    #pragma unroll
    for (int r = 0; r < 4; ++r) {
      const int m = m0 + lg * 4 + r;
      const int n = n0 + nt * 16 + l15;
      const float e = __expf(acc[nt][r] - mr[r]);
      const float a = ((pmmask >> (nt * 4 + r)) & 1) ? e * rinv[r] : 0.f;
      attn_b[(size_t)m * Nn + n] = a;
      pstage[w][lg * 4 + r][nt * 16 + l15] = f2bfu(a);
    }
  }
  __syncthreads();

  // ---- PV: wave w covers tok in [n0, n0+96); A = P from own LDS region ----
  f32x4 pacc[4] = {};
  const ushort_t* vb0 = vbT + (size_t)(bz * 64) * Nn;
  #pragma unroll
  for (int ks = 0; ks < 3; ++ks) {
    const int ktok = ks * 32 + lg * 8;           // local tok offset
    const short8 ap = *(const short8*)&pstage[w][l15][ktok];
    #pragma unroll
    for (int nt = 0; nt < 4; ++nt) {
      const short8 bvv = *(const short8*)(vb0 +
          (size_t)(nt * 16 + l15) * Nn + n0 + ktok);
      pacc[nt] = __builtin_amdgcn_mfma_f32_16x16x32_bf16(ap, bvv, pacc[nt], 0, 0, 0);
    }
  }
  // partials -> LDS
  #pragma unroll
  for (int nt = 0; nt < 4; ++nt)
    #pragma unroll
    for (int r = 0; r < 4; ++r)
      part[w][lg * 4 + r][nt * 16 + l15] = pacc[nt][r];
  __syncthreads();
  // combine + store
  {
    const int o = tid * 4;
    const int row = o >> 6, dh0 = o & 63;
    f32x4 s = *(const f32x4*)&part[0][row][dh0];
    s += *(const f32x4*)&part[1][row][dh0];
    s += *(const f32x4*)&part[2][row][dh0];
    s += *(const f32x4*)&part[3][row][dh0];
    ushort4 st;
    st.x = f2bfu(s[0]); st.y = f2bfu(s[1]); st.z = f2bfu(s[2]); st.w = f2bfu(s[3]);
    *(ushort4*)(aoB + (size_t)(b * Nn + m0 + row) * Dd + h * 64 + dh0) = st;
  }
}

// ---------------------------------------------------------------------------
// FF1 with fused gate: agB = (xnb@ffW1[:512]^T + b_a) * gelu(xnb@ffW1[512:]^T
// + b_g), bf16 out.  grid (8, 24); block = 4 waves; wave: 16(M) x 64(N).
// ---------------------------------------------------------------------------
__global__ __launch_bounds__(256) void ffn1_kernel(
    const ushort_t* __restrict__ xnb, const ushort_t* __restrict__ ffW1B,
    const float* __restrict__ ffb1, ushort_t* __restrict__ agB)
{
  const int tid = threadIdx.x;
  const int lane = tid & 63;
  const int w   = tid >> 6;
  const int l15 = lane & 15, lg = lane >> 4;
  const int m0 = blockIdx.y * 64 + w * 16;
  const int n0 = blockIdx.x * 64;

  f32x4 accA[4] = {}, accG[4] = {};
  const ushort_t* pa = xnb + (size_t)(m0 + l15) * Dd + lg * 8;
  for (int k0 = 0; k0 < Dd; k0 += 32) {
    const short8 af = *(const short8*)(pa + k0);
    #pragma unroll
    for (int nt = 0; nt < 4; ++nt) {
      const short8 bfa = *(const short8*)(ffW1B +
          (size_t)(n0 + nt * 16 + l15) * Dd + k0 + lg * 8);
      const short8 bfg = *(const short8*)(ffW1B +
          (size_t)(512 + n0 + nt * 16 + l15) * Dd + k0 + lg * 8);
      accA[nt] = __builtin_amdgcn_mfma_f32_16x16x32_bf16(af, bfa, accA[nt], 0, 0, 0);
      accG[nt] = __builtin_amdgcn_mfma_f32_16x16x32_bf16(af, bfg, accG[nt], 0, 0, 0);
    }
  }
  #pragma unroll
  for (int nt = 0; nt < 4; ++nt) {
    #pragma unroll
    for (int r = 0; r < 4; ++r) {
      const int m = m0 + lg * 4 + r;
      const int n = n0 + nt * 16 + l15;
      const float a = accA[nt][r] + ffb1[n];
      const float g = accG[nt][r] + ffb1[512 + n];
      agB[(size_t)m * 512 + n] = f2bfu(a * gelu_f(g));
    }
  }
}

// ---------------------------------------------------------------------------
// bf16-operand MFMA GEMM (MODE 0 only): C(f32) = A16 @ B^T (+bias)(+res).
// ---------------------------------------------------------------------------
__global__ __launch_bounds__(256) void gemm2(
    const ushort_t* __restrict__ A16, int lda,
    const ushort_t* __restrict__ Bm, int ldb,
    float* __restrict__ Cc, int ldc,
    const float* __restrict__ bias,
    const float* __restrict__ res, int ldr,
    int K)
{
  const int tid = threadIdx.x;
  const int lane = tid & 63;
  const int w   = tid >> 6;
  const int l15 = lane & 15, lg = lane >> 4;
  const int m0 = blockIdx.y * 64 + w * 16;
  const int n0 = blockIdx.x * 64;

  f32x4 acc[4] = {};
  const ushort_t* pa16 = A16 + (size_t)(m0 + l15) * lda + lg * 8;
  for (int k0 = 0; k0 < K; k0 += 32) {
    const short8 af = *(const short8*)(pa16 + k0);
    #pragma unroll
    for (int nt = 0; nt < 4; ++nt) {
      const short8 bf = *(const short8*)(Bm +
          (size_t)(n0 + nt * 16 + l15) * ldb + k0 + lg * 8);
      acc[nt] = __builtin_amdgcn_mfma_f32_16x16x32_bf16(af, bf, acc[nt], 0, 0, 0);
    }
  }
  #pragma unroll
  for (int nt = 0; nt < 4; ++nt) {
    #pragma unroll
    for (int r = 0; r < 4; ++r) {
      const int m = m0 + lg * 4 + r;
      const int n = n0 + nt * 16 + l15;
      float v = acc[nt][r];
      if (bias) v += bias[n];
      if (res)  v += res[(size_t)m * ldr + n];
      Cc[(size_t)m * ldc + n] = v;
    }
  }
}

// ---------------------------------------------------------------------------
extern "C" void kernel_launch(void* const* d_in, const int* in_sizes, int n_in,
                              void* d_out, int out_size, void* d_ws, size_t ws_size,
                              hipStream_t stream) {
  const float* x    = (const float*)d_in[0];
  const int*   pm   = (const int*)  d_in[1];
  const int*   vld  = (const int*)  d_in[2];
  const float* cont = (const float*)d_in[3];
  const int* dbk = (const int*)d_in[4];
  const int* drk = (const int*)d_in[5];
  const int* rpk = (const int*)d_in[6];
  const int* hdk = (const int*)d_in[7];
  const int* etk = (const int*)d_in[8];
  const int* spk = (const int*)d_in[9];
  const int* sck = (const int*)d_in[10];
  const int* dgk = (const int*)d_in[11];
  const int* ctk = (const int*)d_in[12];
  const float* Wq  = (const float*)d_in[13];
  const float* Wk  = (const float*)d_in[14];
  const float* Wv  = (const float*)d_in[15];
  const float* Wo  = (const float*)d_in[16];
  const float* bo  = (const float*)d_in[17];
  const float* cmW1 = (const float*)d_in[18];
  const float* cmb1 = (const float*)d_in[19];
  const float* cmW2 = (const float*)d_in[20];
  const float* cmb2 = (const float*)d_in[21];
  const float* Ed  = (const float*)d_in[22];
  const float* Edi = (const float*)d_in[23];
  const float* Er  = (const float*)d_in[24];
  const float* Eh  = (const float*)d_in[25];
  const float* Ee  = (const float*)d_in[26];
  const float* Esp = (const float*)d_in[27];
  const float* Edg = (const float*)d_in[28];
  const float* Ec  = (const float*)d_in[29];
  const float* Es  = (const float*)d_in[30];
  const float* blng = (const float*)d_in[31];
  const float* blnb = (const float*)d_in[32];
  const float* bW   = (const float*)d_in[33];
  const float* bb_  = (const float*)d_in[34];
  const float* ln1g = (const float*)d_in[35];
  const float* ln1b = (const float*)d_in[36];
  const float* ln2g = (const float*)d_in[37];
  const float* ln2b = (const float*)d_in[38];
  const float* ffW1 = (const float*)d_in[39];
  const float* ffb1 = (const float*)d_in[40];
  const float* ffW2 = (const float*)d_in[41];
  const float* ffb2 = (const float*)d_in[42];

  float* out   = (float*)d_out;
  float* xout  = out;                       // 393216
  float* attn  = out + 393216;              // 2359296
  float* biasO = out + 393216 + 2359296;    // 2359296

  float* ws = (float*)d_ws;
  // persistent bf16 weights [0, 327680)
  ushort_t* wqB   = (ushort_t*)(ws);             // 65536 ush
  ushort_t* wkB   = (ushort_t*)(ws + 32768);
  ushort_t* wvB   = (ushort_t*)(ws + 65536);
  ushort_t* woB   = (ushort_t*)(ws + 98304);
  ushort_t* ffW1B = (ushort_t*)(ws + 131072);    // 262144 ush
  ushort_t* ffW2B = (ushort_t*)(ws + 262144);    // 131072 ush
  // epoch 1 (pair path; dead after pair_kernel) [327680, 2794304)
  ushort_t* contP = (ushort_t*)(ws + 327680);    // 4718592 ush
  ushort_t* dcP   = (ushort_t*)(ws + 2686976);   // 98304 ush
  ushort_t* dcbP  = (ushort_t*)(ws + 2736128);   // 98304 ush
  ushort_t* EddP  = (ushort_t*)(ws + 2785280);   // 5760 ush
  ushort_t* ErsP  = (ushort_t*)(ws + 2788160);   // 3840 ush
  ushort_t* EhesP = (ushort_t*)(ws + 2790080);   // 3840 ush
  ushort_t* w1bf  = (ushort_t*)(ws + 2792000);   // 512 ush
  ushort_t* w2bf  = (ushort_t*)(ws + 2792256);   // 4096 ush
  // epoch 2 (attention/FFN; lives after pair) [327680, 3276800)
  ushort_t* xnb = (ushort_t*)(ws + 327680);      // 393216 ush
  ushort_t* qbB = (ushort_t*)(ws + 524288);
  ushort_t* kbB = (ushort_t*)(ws + 720896);
  ushort_t* vbT = (ushort_t*)(ws + 917504);
  ushort_t* aoB = (ushort_t*)(ws + 1114112);
  float* x1  = ws + 1310720;                     // 393216 f32
  ushort_t* agB = (ushort_t*)(ws + 1703936);     // 786432 ush

  // 0) prep + pack (merged)
  prep_kernel<<<3062, 256, 0, stream>>>(dgk, ctk, Edg, Ec, cmb2, cmW1, cmb1,
      cmW2, Ed, Edi, Er, Eh, Ee, Esp, Es, Wq, Wk, Wv, Wo, ffW1, ffW2,
      dbk, drk, rpk, hdk, etk, spk, sck, pm, cont,
      dcP, dcbP, w1bf, w2bf, EddP, ErsP, EhesP,
      wqB, wkB, wvB, woB, ffW1B, ffW2B, contP);
  // 1) pair bias (MFMA, 2 tiles/wave, 4 waves/SIMD)
  pair_kernel<<<4608, 256, 0, stream>>>(contP, w1bf, w2bf, EddP, ErsP, EhesP,
      blng, blnb, bW, bb_, dcP, dcbP, biasO);
  // 2) ln1 -> xnb (bf16)
  ln_kernel<<<384, 256, 0, stream>>>(x, ln1g, ln1b, xnb);
  // 3) q, k, V^T projections (all-bf16)
  qkv_kernel<<<dim3(4, 24, 3), 256, 0, stream>>>(xnb, wqB, wkB, wvB,
      qbB, kbB, vbT);
  // 4) fused attention: QK^T + softmax + attn write + PV -> aoB
  attn_kernel<<<dim3(24, 16), 256, 0, stream>>>(qbB, kbB, vbT, biasO, pm, vld,
      attn, aoB);
  // 5) Wo + bo + residual(x) -> x1
  gemm2<<<dim3(4, 24), 256, 0, stream>>>(aoB, 256, woB, 256,
      x1, 256, bo, x, 256, 256);
  // 6) ln2 -> xnb
  ln_kernel<<<384, 256, 0, stream>>>(x1, ln2g, ln2b, xnb);
  // 7) FF1 with fused gate -> agB (bf16)
  ffn1_kernel<<<dim3(8, 24), 256, 0, stream>>>(xnb, ffW1B, ffb1, agB);
  // 8) FF2 + ffb2 + residual(x1) -> x_out
  gemm2<<<dim3(4, 24), 256, 0, stream>>>(agB, 512, ffW2B, 512,
      xout, 256, ffb2, x1, 256, 512);
}

// Round 19
// 177.020 us; speedup vs baseline: 1.0489x; 1.0489x over previous
//
#include <hip/hip_runtime.h>
#include <hip/hip_bf16.h>
#include <float.h>

// Problem constants
#define Bz   4
#define Nn   384
#define Dd   256
#define Hh   4
#define DHh  64
#define NSQ  (384*384)
#define NEG_MAX (-3.40282346638528859812e+38f)

typedef __attribute__((ext_vector_type(8))) short short8;
typedef __attribute__((ext_vector_type(4))) float f32x4;
typedef unsigned short ushort_t;

// fast exact-gelu: erf via Abramowitz-Stegun 7.1.26 (|err| <= 1.5e-7)
__device__ __forceinline__ float gelu_f(float x){
  const float y = __builtin_fabsf(x) * 0.70710678118654752f;
  const float t = __builtin_amdgcn_rcpf(fmaf(0.3275911f, y, 1.0f));
  float poly = fmaf(1.061405429f, t, -1.453152027f);
  poly = fmaf(poly, t, 1.421413741f);
  poly = fmaf(poly, t, -0.284496736f);
  poly = fmaf(poly, t, 0.254829592f);
  poly *= t;
  const float e = __expf(-y * y);
  const float erfa = fmaf(-poly, e, 1.0f);
  const float er = __builtin_copysignf(erfa, x);
  return 0.5f * x * (1.0f + er);
}
__device__ __forceinline__ float wsum(float v){
  #pragma unroll
  for (int o = 32; o > 0; o >>= 1) v += __shfl_xor(v, o, 64);
  return v;
}
__device__ __forceinline__ float4 ld4(const float* p){ return *(const float4*)p; }
__device__ __forceinline__ f32x4 ldv4(const float* p){ return *(const f32x4*)p; }

// fp32 <-> bf16
__device__ __forceinline__ ushort_t f2bfu(float f){
  union { float f; unsigned u; } v; v.f = f;
  unsigned r = v.u + 0x7FFFu + ((v.u >> 16) & 1u);
  return (ushort_t)(r >> 16);
}
__device__ __forceinline__ short f2bf(float f){ return (short)f2bfu(f); }
__device__ __forceinline__ float bfe2f(ushort_t u){
  union { unsigned u; float f; } v; v.u = ((unsigned)u) << 16; return v.f;
}
__device__ __forceinline__ void addbf(f32x4& a, f32x4& b, short8 v){
  a[0] += bfe2f((ushort_t)v[0]); a[1] += bfe2f((ushort_t)v[1]);
  a[2] += bfe2f((ushort_t)v[2]); a[3] += bfe2f((ushort_t)v[3]);
  b[0] += bfe2f((ushort_t)v[4]); b[1] += bfe2f((ushort_t)v[5]);
  b[2] += bfe2f((ushort_t)v[6]); b[3] += bfe2f((ushort_t)v[7]);
}

// ---------------------------------------------------------------------------
// prep (merged with pack): permuted bf16 tables, w1bf/w2bf, bf16 weights,
// and per-pair 16B records contP.
// ---------------------------------------------------------------------------
__global__ __launch_bounds__(256) void prep_kernel(
    const int* __restrict__ dgk, const int* __restrict__ ctk,
    const float* __restrict__ Edg, const float* __restrict__ Ec,
    const float* __restrict__ b2,
    const float* __restrict__ W1, const float* __restrict__ b1,
    const float* __restrict__ W2,
    const float* __restrict__ Ed, const float* __restrict__ Edi,
    const float* __restrict__ Er, const float* __restrict__ Eh,
    const float* __restrict__ Ee, const float* __restrict__ Esp,
    const float* __restrict__ Es,
    const float* __restrict__ Wq, const float* __restrict__ Wk,
    const float* __restrict__ Wv, const float* __restrict__ Wo,
    const float* __restrict__ ffW1, const float* __restrict__ ffW2,
    const int* __restrict__ dbk, const int* __restrict__ drk,
    const int* __restrict__ rpk, const int* __restrict__ hdk,
    const int* __restrict__ etk, const int* __restrict__ spk,
    const int* __restrict__ sck, const int* __restrict__ pm,
    const float* __restrict__ cont,
    ushort_t* __restrict__ dcP, ushort_t* __restrict__ dcbP,
    ushort_t* __restrict__ w1bf, ushort_t* __restrict__ w2bf,
    ushort_t* __restrict__ EddP, ushort_t* __restrict__ ErsP,
    ushort_t* __restrict__ EhesP,
    ushort_t* __restrict__ wqB, ushort_t* __restrict__ wkB,
    ushort_t* __restrict__ wvB, ushort_t* __restrict__ woB,
    ushort_t* __restrict__ ffW1B, ushort_t* __restrict__ ffW2B,
    ushort_t* __restrict__ contP)
{
  const int idx = blockIdx.x * 256 + threadIdx.x;
  if (idx < 24576) {                       // dcP / dcbP (permuted bf16)
    const int row = idx >> 4;
    const int q   = (idx & 15) << 2;
    const int pos = ((q >> 2) & 3) * 16 + (q >> 4) * 4;
    const float4 a = ld4(Edg + (dgk[row] << 6) + q);
    const float4 b = ld4(Ec  + (ctk[row] << 6) + q);
    const float4 bb4 = ld4(b2 + q);
    ushort4 o, o2;
    o.x = f2bfu(a.x + b.x); o.y = f2bfu(a.y + b.y);
    o.z = f2bfu(a.z + b.z); o.w = f2bfu(a.w + b.w);
    o2.x = f2bfu(a.x + b.x + bb4.x); o2.y = f2bfu(a.y + b.y + bb4.y);
    o2.z = f2bfu(a.z + b.z + bb4.z); o2.w = f2bfu(a.w + b.w + bb4.w);
    *(ushort4*)(dcP  + row * 64 + pos) = o;
    *(ushort4*)(dcbP + row * 64 + pos) = o2;
  } else if (idx < 26624) {                // w2bf [c][k]
    const int t = idx - 24576;
    const int c = t >> 5, k2 = (t & 31) << 1;
    w2bf[c * 64 + k2]     = f2bfu(W2[c * 64 + k2]);
    w2bf[c * 64 + k2 + 1] = f2bfu(W2[c * 64 + k2 + 1]);
  } else if (idx < 26688) {                // w1bf {W1 row, b1, 0} bf16
    const int k = idx - 26624;
    #pragma unroll
    for (int d = 0; d < 6; ++d) w1bf[k * 8 + d] = f2bfu(W1[k * 6 + d]);
    w1bf[k * 8 + 6] = f2bfu(b1[k]);
    w1bf[k * 8 + 7] = 0;
  } else if (idx < 28128) {                // EddP: 90 rows, permuted bf16
    const int t = idx - 26688;
    const int row = t >> 4, q = (t & 15) << 2;
    const int pos = ((q >> 2) & 3) * 16 + (q >> 4) * 4;
    const int d = row / 10, r = row - d * 10;
    const float4 a = ld4(Ed + (d << 6) + q);
    const float4 b = ld4(Edi + (r << 6) + q);
    ushort4 o;
    o.x = f2bfu(a.x + b.x); o.y = f2bfu(a.y + b.y);
    o.z = f2bfu(a.z + b.z); o.w = f2bfu(a.w + b.w);
    *(ushort4*)(EddP + row * 64 + pos) = o;
  } else if (idx < 29088) {                // ErsP: 60 rows
    const int t = idx - 28128;
    const int row = t >> 4, q = (t & 15) << 2;
    const int pos = ((q >> 2) & 3) * 16 + (q >> 4) * 4;
    const int ro = row / 6, s = row - ro * 6;
    const float4 a = ld4(Er + (ro << 6) + q);
    const float4 b = ld4(Esp + (s << 6) + q);
    ushort4 o;
    o.x = f2bfu(a.x + b.x); o.y = f2bfu(a.y + b.y);
    o.z = f2bfu(a.z + b.z); o.w = f2bfu(a.w + b.w);
    *(ushort4*)(ErsP + row * 64 + pos) = o;
  } else if (idx < 30048) {                // EhesP: 60 rows
    const int t = idx - 29088;
    const int row = t >> 4, q = (t & 15) << 2;
    const int pos = ((q >> 2) & 3) * 16 + (q >> 4) * 4;
    const int h = row / 15, rem = row - h * 15;
    const int e = rem / 3, sm = rem - e * 3;
    const float4 a = ld4(Eh + (h << 6) + q);
    const float4 b = ld4(Ee + (e << 6) + q);
    const float4 c = ld4(Es + (sm << 6) + q);
    ushort4 o;
    o.x = f2bfu(a.x + b.x + c.x); o.y = f2bfu(a.y + b.y + c.y);
    o.z = f2bfu(a.z + b.z + c.z); o.w = f2bfu(a.w + b.w + c.w);
    *(ushort4*)(EhesP + row * 64 + pos) = o;
  } else if (idx < 193888) {               // weight bf16 packs, 4 elems/thread
    const int t = idx - 30048;
    const float* src; ushort_t* dst; int e;
    if (t < 16384)      { src = Wq;   dst = wqB;   e = t << 2; }
    else if (t < 32768) { src = Wk;   dst = wkB;   e = (t - 16384) << 2; }
    else if (t < 49152) { src = Wv;   dst = wvB;   e = (t - 32768) << 2; }
    else if (t < 65536) { src = Wo;   dst = woB;   e = (t - 49152) << 2; }
    else if (t < 131072){ src = ffW1; dst = ffW1B; e = (t - 65536) << 2; }
    else                { src = ffW2; dst = ffW2B; e = (t - 131072) << 2; }
    const float4 v = ld4(src + e);
    ushort4 o;
    o.x = f2bfu(v.x); o.y = f2bfu(v.y); o.z = f2bfu(v.z); o.w = f2bfu(v.w);
    *(ushort4*)(dst + e) = o;
  } else if (idx < 193888 + Bz * Nn * Nn) { // pack: per-pair 16B record
    const int p = idx - 193888;
    const float* cp = cont + (size_t)p * 6;
    short8 r;
    r[0] = f2bf(cp[0]); r[1] = f2bf(cp[1]); r[2] = f2bf(cp[2]);
    r[3] = f2bf(cp[3]); r[4] = f2bf(cp[4]); r[5] = f2bf(cp[5]);
    const unsigned iv = (unsigned)(dbk[p] * 10 + drk[p])
                      | ((unsigned)(rpk[p] * 6 + spk[p]) << 7)
                      | ((unsigned)((hdk[p] * 5 + etk[p]) * 3 + sck[p]) << 13)
                      | ((pm[p] ? 1u : 0u) << 19);
    r[6] = (short)(iv & 0xffffu);
    r[7] = (short)(iv >> 16);
    *(short8*)(contP + (size_t)p * 8) = r;
  }
}

// ---------------------------------------------------------------------------
// Fused pair kernel v13 (R17 optimum): 3 tiles/wave (48 pairs), (256,3).
// Measured: VGPR=84, no spill, Occ ~29%, VALUBusy ~64%, ~90.6 us.
// ---------------------------------------------------------------------------
__global__ __launch_bounds__(256, 3) void pair_kernel(
    const ushort_t* __restrict__ contP,
    const ushort_t* __restrict__ w1bf, const ushort_t* __restrict__ w2bf,
    const ushort_t* __restrict__ EddP, const ushort_t* __restrict__ ErsP,
    const ushort_t* __restrict__ EhesP,
    const float* __restrict__ lng, const float* __restrict__ lnb,
    const float* __restrict__ bW, const float* __restrict__ bb,
    const ushort_t* __restrict__ dcP, const ushort_t* __restrict__ dcbP,
    float* __restrict__ biasOut)
{
  const int tid  = threadIdx.x;
  const int lane = tid & 63;
  const int l15  = lane & 15, lg = lane >> 4;
  const int wid  = blockIdx.x * 4 + (tid >> 6);             // [0, 12288)
  const int rowU = __builtin_amdgcn_readfirstlane(wid >> 3); // b*N+i
  const int jb   = wid & 7;
  const int b    = rowU / Nn;
  const int i    = rowU - b * Nn;
  const int j0   = jb * 48 + l15;
  const size_t pbase = (size_t)rowU * Nn + j0;
  const int colOff = lg << 2;

  const short8 rec0 = *(const short8*)(contP + (pbase + 0) * 8);
  const short8 rec1 = *(const short8*)(contP + (pbase + 16) * 8);
  const short8 rec2 = *(const short8*)(contP + (pbase + 32) * 8);
  asm volatile("" :: "v"(rec0), "v"(rec1), "v"(rec2));
  const unsigned ix0 = (unsigned)(ushort_t)rec0[6] | ((unsigned)(ushort_t)rec0[7] << 16);
  const unsigned ix1 = (unsigned)(ushort_t)rec1[6] | ((unsigned)(ushort_t)rec1[7] << 16);
  const unsigned ix2 = (unsigned)(ushort_t)rec2[6] | ((unsigned)(ushort_t)rec2[7] << 16);
  const float c00 = bfe2f((ushort_t)rec0[0]), c01 = bfe2f((ushort_t)rec0[1]),
              c02 = bfe2f((ushort_t)rec0[2]), c03 = bfe2f((ushort_t)rec0[3]),
              c04 = bfe2f((ushort_t)rec0[4]), c05 = bfe2f((ushort_t)rec0[5]);
  const float c10 = bfe2f((ushort_t)rec1[0]), c11 = bfe2f((ushort_t)rec1[1]),
              c12 = bfe2f((ushort_t)rec1[2]), c13 = bfe2f((ushort_t)rec1[3]),
              c14 = bfe2f((ushort_t)rec1[4]), c15 = bfe2f((ushort_t)rec1[5]);
  const float c20 = bfe2f((ushort_t)rec2[0]), c21 = bfe2f((ushort_t)rec2[1]),
              c22 = bfe2f((ushort_t)rec2[2]), c23 = bfe2f((ushort_t)rec2[3]),
              c24 = bfe2f((ushort_t)rec2[4]), c25 = bfe2f((ushort_t)rec2[5]);

  short8 b0a, b0b, b1a, b1b, b2a, b2b;
#define H1ROW(R, JJ, D0, D1, D2) { \
    const float w0 = bfe2f((ushort_t)R[0]), w1 = bfe2f((ushort_t)R[1]), \
                w2 = bfe2f((ushort_t)R[2]), w3 = bfe2f((ushort_t)R[3]), \
                w4 = bfe2f((ushort_t)R[4]), w5 = bfe2f((ushort_t)R[5]), \
                w6 = bfe2f((ushort_t)R[6]); \
    float s0 = w6, s1 = w6, s2 = w6; \
    s0 = fmaf(w0, c00, s0); s0 = fmaf(w1, c01, s0); s0 = fmaf(w2, c02, s0); \
    s0 = fmaf(w3, c03, s0); s0 = fmaf(w4, c04, s0); s0 = fmaf(w5, c05, s0); \
    s1 = fmaf(w0, c10, s1); s1 = fmaf(w1, c11, s1); s1 = fmaf(w2, c12, s1); \
    s1 = fmaf(w3, c13, s1); s1 = fmaf(w4, c14, s1); s1 = fmaf(w5, c15, s1); \
    s2 = fmaf(w0, c20, s2); s2 = fmaf(w1, c21, s2); s2 = fmaf(w2, c22, s2); \
    s2 = fmaf(w3, c23, s2); s2 = fmaf(w4, c24, s2); s2 = fmaf(w5, c25, s2); \
    D0[JJ] = f2bf(gelu_f(s0)); D1[JJ] = f2bf(gelu_f(s1)); \
    D2[JJ] = f2bf(gelu_f(s2)); }
  {
    const ushort_t* wb_ = w1bf + ((lg << 3) << 3);
    const short8 r0 = *(const short8*)(wb_ +  0);
    const short8 r1 = *(const short8*)(wb_ +  8);
    const short8 r2 = *(const short8*)(wb_ + 16);
    const short8 r3 = *(const short8*)(wb_ + 24);
    const short8 r4 = *(const short8*)(wb_ + 32);
    const short8 r5 = *(const short8*)(wb_ + 40);
    const short8 r6 = *(const short8*)(wb_ + 48);
    const short8 r7 = *(const short8*)(wb_ + 56);
    asm volatile("" :: "v"(r0), "v"(r1), "v"(r2), "v"(r3),
                       "v"(r4), "v"(r5), "v"(r6), "v"(r7));
    H1ROW(r0, 0, b0a, b1a, b2a) H1ROW(r1, 1, b0a, b1a, b2a)
    H1ROW(r2, 2, b0a, b1a, b2a) H1ROW(r3, 3, b0a, b1a, b2a)
    H1ROW(r4, 4, b0a, b1a, b2a) H1ROW(r5, 5, b0a, b1a, b2a)
    H1ROW(r6, 6, b0a, b1a, b2a) H1ROW(r7, 7, b0a, b1a, b2a)
  }
  {
    const ushort_t* wb_ = w1bf + ((32 + (lg << 3)) << 3);
    const short8 r0 = *(const short8*)(wb_ +  0);
    const short8 r1 = *(const short8*)(wb_ +  8);
    const short8 r2 = *(const short8*)(wb_ + 16);
    const short8 r3 = *(const short8*)(wb_ + 24);
    const short8 r4 = *(const short8*)(wb_ + 32);
    const short8 r5 = *(const short8*)(wb_ + 40);
    const short8 r6 = *(const short8*)(wb_ + 48);
    const short8 r7 = *(const short8*)(wb_ + 56);
    asm volatile("" :: "v"(r0), "v"(r1), "v"(r2), "v"(r3),
                       "v"(r4), "v"(r5), "v"(r6), "v"(r7));
    H1ROW(r0, 0, b0b, b1b, b2b) H1ROW(r1, 1, b0b, b1b, b2b)
    H1ROW(r2, 2, b0b, b1b, b2b) H1ROW(r3, 3, b0b, b1b, b2b)
    H1ROW(r4, 4, b0b, b1b, b2b) H1ROW(r5, 5, b0b, b1b, b2b)
    H1ROW(r6, 6, b0b, b1b, b2b) H1ROW(r7, 7, b0b, b1b, b2b)
  }
#undef H1ROW

  const ushort_t* wbase = w2bf + (size_t)l15 * 64 + (lg << 3);
  const short8 wa0 = *(const short8*)(wbase);
  const short8 wc0 = *(const short8*)(wbase + 32);
  const short8 wa1 = *(const short8*)(wbase + 16 * 64);
  const short8 wc1 = *(const short8*)(wbase + 16 * 64 + 32);
  const short8 wa2 = *(const short8*)(wbase + 32 * 64);
  const short8 wc2 = *(const short8*)(wbase + 32 * 64 + 32);
  const short8 wa3 = *(const short8*)(wbase + 48 * 64);
  const short8 wc3 = *(const short8*)(wbase + 48 * 64 + 32);
  asm volatile("" :: "v"(wa0), "v"(wc0), "v"(wa1), "v"(wc1),
                     "v"(wa2), "v"(wc2), "v"(wa3), "v"(wc3));
  f32x4 acc0[4] = {}, acc1[4] = {}, acc2[4] = {};
#define MM(ACC, BA, BB) \
  ACC[0] = __builtin_amdgcn_mfma_f32_16x16x32_bf16(wa0, BA, ACC[0], 0, 0, 0); \
  ACC[0] = __builtin_amdgcn_mfma_f32_16x16x32_bf16(wc0, BB, ACC[0], 0, 0, 0); \
  ACC[1] = __builtin_amdgcn_mfma_f32_16x16x32_bf16(wa1, BA, ACC[1], 0, 0, 0); \
  ACC[1] = __builtin_amdgcn_mfma_f32_16x16x32_bf16(wc1, BB, ACC[1], 0, 0, 0); \
  ACC[2] = __builtin_amdgcn_mfma_f32_16x16x32_bf16(wa2, BA, ACC[2], 0, 0, 0); \
  ACC[2] = __builtin_amdgcn_mfma_f32_16x16x32_bf16(wc2, BB, ACC[2], 0, 0, 0); \
  ACC[3] = __builtin_amdgcn_mfma_f32_16x16x32_bf16(wa3, BA, ACC[3], 0, 0, 0); \
  ACC[3] = __builtin_amdgcn_mfma_f32_16x16x32_bf16(wc3, BB, ACC[3], 0, 0, 0);
  MM(acc0, b0a, b0b) MM(acc1, b1a, b1b) MM(acc2, b2a, b2b)
#undef MM

#define GATHER(ACC, IX, JOFF) { \
    const int xdd  = ((IX) & 127) << 6; \
    const int xrs  = (((IX) >> 7) & 63) << 6; \
    const int xhes = (((IX) >> 13) & 63) << 6; \
    const ushort_t* ep = EddP  + xdd  + (lg << 4); \
    const ushort_t* rp = ErsP  + xrs  + (lg << 4); \
    const ushort_t* hp = EhesP + xhes + (lg << 4); \
    const ushort_t* jp = dcP + (((size_t)(b * Nn + j0 + (JOFF))) << 6) + (lg << 4); \
    const short8 e0 = *(const short8*)ep,       e1 = *(const short8*)(ep + 8); \
    const short8 r0 = *(const short8*)rp,       r1 = *(const short8*)(rp + 8); \
    const short8 h0 = *(const short8*)hp,       h1 = *(const short8*)(hp + 8); \
    const short8 jv0 = *(const short8*)jp,      jv1 = *(const short8*)(jp + 8); \
    asm volatile("" :: "v"(e0), "v"(e1), "v"(r0), "v"(r1), \
                       "v"(h0), "v"(h1), "v"(jv0), "v"(jv1)); \
    addbf(ACC[0], ACC[1], e0);  addbf(ACC[2], ACC[3], e1); \
    addbf(ACC[0], ACC[1], r0);  addbf(ACC[2], ACC[3], r1); \
    addbf(ACC[0], ACC[1], h0);  addbf(ACC[2], ACC[3], h1); \
    addbf(ACC[0], ACC[1], jv0); addbf(ACC[2], ACC[3], jv1); }
  GATHER(acc0, ix0, 0)
  GATHER(acc1, ix1, 16)
  GATHER(acc2, ix2, 32)
#undef GATHER
  {
    const ushort_t* up = dcbP + (((size_t)rowU) << 6) + (lg << 4);
    const short8 u0 = *(const short8*)up, u1 = *(const short8*)(up + 8);
    f32x4 du0, du1, du2, du3;
    #pragma unroll
    for (int r = 0; r < 4; ++r) {
      du0[r] = bfe2f((ushort_t)u0[r]);     du1[r] = bfe2f((ushort_t)u0[4 + r]);
      du2[r] = bfe2f((ushort_t)u1[r]);     du3[r] = bfe2f((ushort_t)u1[4 + r]);
    }
    acc0[0] += du0; acc0[1] += du1; acc0[2] += du2; acc0[3] += du3;
    acc1[0] += du0; acc1[1] += du1; acc1[2] += du2; acc1[3] += du3;
    acc2[0] += du0; acc2[1] += du1; acc2[2] += du2; acc2[3] += du3;
  }

  float mean0, inv0, mean1, inv1, mean2, inv2;
#define STATS(ACC, MEAN, INV) { \
    float sum = 0.f, sq = 0.f; \
    _Pragma("unroll") \
    for (int mt = 0; mt < 4; ++mt) \
      _Pragma("unroll") \
      for (int r = 0; r < 4; ++r) { \
        const float v = ACC[mt][r]; sum += v; sq = fmaf(v, v, sq); } \
    sum += __shfl_xor(sum, 16, 64); sum += __shfl_xor(sum, 32, 64); \
    sq  += __shfl_xor(sq,  16, 64); sq  += __shfl_xor(sq,  32, 64); \
    MEAN = sum * (1.f / 64.f); \
    INV  = rsqrtf(sq * (1.f / 64.f) - MEAN * MEAN + 1e-5f); }
  STATS(acc0, mean0, inv0) STATS(acc1, mean1, inv1) STATS(acc2, mean2, inv2)
#undef STATS

  float h00 = 0.f, h01 = 0.f, h02 = 0.f, h03 = 0.f;
  float h10 = 0.f, h11 = 0.f, h12 = 0.f, h13 = 0.f;
  float h20 = 0.f, h21 = 0.f, h22 = 0.f, h23 = 0.f;
  #pragma unroll
  for (int mt = 0; mt < 4; ++mt) {
    const int c0i = (mt << 4) + colOff;
    const f32x4 g4 = ldv4(lng + c0i);
    const f32x4 b4 = ldv4(lnb + c0i);
    const f32x4 w0 = ldv4(bW + c0i);
    const f32x4 w1_ = ldv4(bW + 64 + c0i);
    const f32x4 w2_ = ldv4(bW + 128 + c0i);
    const f32x4 w3_ = ldv4(bW + 192 + c0i);
    asm volatile("" :: "v"(g4), "v"(b4), "v"(w0), "v"(w1_), "v"(w2_), "v"(w3_));
    #pragma unroll
    for (int r = 0; r < 4; ++r) {
      float g;
      g = gelu_f((acc0[mt][r] - mean0) * inv0 * g4[r] + b4[r]);
      h00 = fmaf(w0[r], g, h00); h01 = fmaf(w1_[r], g, h01);
      h02 = fmaf(w2_[r], g, h02); h03 = fmaf(w3_[r], g, h03);
      g = gelu_f((acc1[mt][r] - mean1) * inv1 * g4[r] + b4[r]);
      h10 = fmaf(w0[r], g, h10); h11 = fmaf(w1_[r], g, h11);
      h12 = fmaf(w2_[r], g, h12); h13 = fmaf(w3_[r], g, h13);
      g = gelu_f((acc2[mt][r] - mean2) * inv2 * g4[r] + b4[r]);
      h20 = fmaf(w0[r], g, h20); h21 = fmaf(w1_[r], g, h21);
      h22 = fmaf(w2_[r], g, h22); h23 = fmaf(w3_[r], g, h23);
    }
  }
#define RED(H) H += __shfl_xor(H, 16, 64); H += __shfl_xor(H, 32, 64);
  RED(h00) RED(h01) RED(h02) RED(h03)
  RED(h10) RED(h11) RED(h12) RED(h13)
  RED(h20) RED(h21) RED(h22) RED(h23)
#undef RED

  const float bbl = bb[lg];
  const float bh0 = ((lg == 0) ? h00 : (lg == 1) ? h01 : (lg == 2) ? h02 : h03) + bbl;
  const float bh1 = ((lg == 0) ? h10 : (lg == 1) ? h11 : (lg == 2) ? h12 : h13) + bbl;
  const float bh2 = ((lg == 0) ? h20 : (lg == 1) ? h21 : (lg == 2) ? h22 : h23) + bbl;
  const size_t base = (size_t)b * (Hh * NSQ) + (size_t)lg * NSQ + (size_t)i * Nn;
  biasOut[base + j0]      = bh0 * (((ix0 >> 19) & 1) ? 1.f : 0.f);
  biasOut[base + j0 + 16] = bh1 * (((ix1 >> 19) & 1) ? 1.f : 0.f);
  biasOut[base + j0 + 32] = bh2 * (((ix2 >> 19) & 1) ? 1.f : 0.f);
}

// ---------------------------------------------------------------------------
// LayerNorm over last dim (256), bf16 output. One wave per row.
// ---------------------------------------------------------------------------
__global__ __launch_bounds__(256) void ln_kernel(
    const float* __restrict__ x, const float* __restrict__ g,
    const float* __restrict__ bta, ushort_t* __restrict__ o)
{
  const int row  = blockIdx.x * 4 + (threadIdx.x >> 6);
  const int lane = threadIdx.x & 63;
  const float4 v = *(const float4*)(x + (size_t)row * Dd + lane * 4);
  float s = v.x + v.y + v.z + v.w;
  s = wsum(s);
  const float m = s * (1.f / 256.f);
  const float dx = v.x - m, dy = v.y - m, dz = v.z - m, dw = v.w - m;
  float q = dx*dx + dy*dy + dz*dz + dw*dw;
  q = wsum(q);
  const float inv = rsqrtf(q * (1.f / 256.f) + 1e-5f);
  const int d = lane * 4;
  const float4 gg = *(const float4*)(g + d);
  const float4 bb = *(const float4*)(bta + d);
  ushort4 out;
  out.x = f2bfu(dx * inv * gg.x + bb.x);
  out.y = f2bfu(dy * inv * gg.y + bb.y);
  out.z = f2bfu(dz * inv * gg.z + bb.z);
  out.w = f2bfu(dw * inv * gg.w + bb.w);
  *(ushort4*)(o + (size_t)row * Dd + d) = out;
}

// ---------------------------------------------------------------------------
// Fused QKV: all-bf16 fragments. z: {wqB->qbB, wkB->kbB, wvB->vbT}.
// ---------------------------------------------------------------------------
__global__ __launch_bounds__(256) void qkv_kernel(
    const ushort_t* __restrict__ xnb,
    const ushort_t* __restrict__ wqB, const ushort_t* __restrict__ wkB,
    const ushort_t* __restrict__ wvB,
    ushort_t* __restrict__ qbB, ushort_t* __restrict__ kbB,
    ushort_t* __restrict__ vbT)
{
  const int tid = threadIdx.x;
  const int lane = tid & 63;
  const int w   = tid >> 6;
  const int l15 = lane & 15, lg = lane >> 4;
  const int m0 = blockIdx.y * 64 + w * 16;
  const int n0 = blockIdx.x * 64;
  const int z  = blockIdx.z;
  const ushort_t* Bb = (z == 0) ? wqB : (z == 1) ? wkB : wvB;

  f32x4 acc[4] = {};
  const ushort_t* pa = xnb + (size_t)(m0 + l15) * Dd + lg * 8;
  for (int k0 = 0; k0 < Dd; k0 += 32) {
    const short8 af = *(const short8*)(pa + k0);
    #pragma unroll
    for (int nt = 0; nt < 4; ++nt) {
      const short8 bf = *(const short8*)(Bb +
          (size_t)(n0 + nt * 16 + l15) * Dd + k0 + lg * 8);
      acc[nt] = __builtin_amdgcn_mfma_f32_16x16x32_bf16(af, bf, acc[nt], 0, 0, 0);
    }
  }
  if (z < 2) {
    ushort_t* Cb = (z == 0) ? qbB : kbB;
    #pragma unroll
    for (int nt = 0; nt < 4; ++nt)
      #pragma unroll
      for (int r = 0; r < 4; ++r)
        Cb[(size_t)(m0 + lg * 4 + r) * Dd + n0 + nt * 16 + l15] = f2bfu(acc[nt][r]);
  } else {
    const int m = m0 + (lg << 2);
    const int b = m / Nn, tok = m - b * Nn;
    #pragma unroll
    for (int nt = 0; nt < 4; ++nt) {
      const int n = n0 + nt * 16 + l15;
      const int h = n >> 6, dh = n & 63;
      ushort4 s4;
      s4.x = f2bfu(acc[nt][0]); s4.y = f2bfu(acc[nt][1]);
      s4.z = f2bfu(acc[nt][2]); s4.w = f2bfu(acc[nt][3]);
      *(ushort4*)(vbT + ((size_t)((b * 4 + h) * 64 + dh)) * Nn + tok) = s4;
    }
  }
}

// ---------------------------------------------------------------------------
// Fused attention: QK^T + bias + safe-mask + softmax + pair-mask renorm +
// attn write + PV, one block per (16-row tile, bz). 4 waves; wave w owns
// 96 columns. P staged per-wave in LDS for the PV transpose.
// ---------------------------------------------------------------------------
__global__ __launch_bounds__(256) void attn_kernel(
    const ushort_t* __restrict__ qbB, const ushort_t* __restrict__ kbB,
    const ushort_t* __restrict__ vbT,
    const float* __restrict__ biasO, const int* __restrict__ pm,
    const int* __restrict__ vld,
    float* __restrict__ attn, ushort_t* __restrict__ aoB)
{
  __shared__ float stats[3][4][16];
  __shared__ float part[4][16][64];          // 16 KB
  __shared__ ushort_t pstage[4][16][104];    // 13 KB
  const int tid = threadIdx.x;
  const int lane = tid & 63, w = tid >> 6;
  const int l15 = lane & 15, lg = lane >> 4;
  const int bz = blockIdx.y, b = bz >> 2, h = bz & 3;
  const int m0 = blockIdx.x * 16;
  const int n0 = w * 96;

  // ---- QK^T: 16 x 96 logits per wave ----
  f32x4 acc[6];
  const ushort_t* paq = qbB + ((size_t)(b * Nn + m0 + l15)) * Dd + h * DHh;
  const short8 aq0 = *(const short8*)(paq + lg * 8);
  const short8 aq1 = *(const short8*)(paq + 32 + lg * 8);
  #pragma unroll
  for (int nt = 0; nt < 6; ++nt) {
    const ushort_t* pk = kbB + ((size_t)(b * Nn + n0 + nt * 16 + l15)) * Dd
                       + h * DHh + lg * 8;
    const short8 bk0 = *(const short8*)pk;
    const short8 bk1 = *(const short8*)(pk + 32);
    f32x4 a = {};
    a = __builtin_amdgcn_mfma_f32_16x16x32_bf16(aq0, bk0, a, 0, 0, 0);
    a = __builtin_amdgcn_mfma_f32_16x16x32_bf16(aq1, bk1, a, 0, 0, 0);
    acc[nt] = a;
  }

  // ---- bias + safe mask (in place in acc), pm bits packed ----
  const float* bias_r = biasO + (size_t)bz * NSQ;
  const int* pm_b = pm + (size_t)b * NSQ;
  int vldv[4];
  #pragma unroll
  for (int r = 0; r < 4; ++r) vldv[r] = vld[b * Nn + m0 + lg * 4 + r];
  unsigned pmmask = 0;
  #pragma unroll
  for (int nt = 0; nt < 6; ++nt) {
    #pragma unroll
    for (int r = 0; r < 4; ++r) {
      const int m = m0 + lg * 4 + r;
      const int n = n0 + nt * 16 + l15;
      const size_t off = (size_t)m * Nn + n;
      const float bv = bias_r[off];
      const int q = pm_b[off];
      const bool sf = (q != 0) || (vldv[r] == 0 && m == n);
      if (q) pmmask |= 1u << (nt * 4 + r);
      acc[nt][r] = sf ? fmaf(acc[nt][r], 0.125f, bv) : NEG_MAX;
    }
  }

  // ---- per-row stats over this wave's 96 cols ----
  float mx[4], sr[4], spr[4];
  #pragma unroll
  for (int r = 0; r < 4; ++r) {
    float m_ = NEG_MAX;
    #pragma unroll
    for (int nt = 0; nt < 6; ++nt) m_ = fmaxf(m_, acc[nt][r]);
    #pragma unroll
    for (int o = 1; o <= 8; o <<= 1) m_ = fmaxf(m_, __shfl_xor(m_, o, 64));
    float s_ = 0.f, sp_ = 0.f;
    #pragma unroll
    for (int nt = 0; nt < 6; ++nt) {
      const float e = __expf(acc[nt][r] - m_);
      s_ += e;
      sp_ += ((pmmask >> (nt * 4 + r)) & 1) ? e : 0.f;
    }
    #pragma unroll
    for (int o = 1; o <= 8; o <<= 1) {
      s_ += __shfl_xor(s_, o, 64);
      sp_ += __shfl_xor(sp_, o, 64);
    }
    mx[r] = m_; sr[r] = s_; spr[r] = sp_;
  }
  if (l15 == 0) {
    #pragma unroll
    for (int r = 0; r < 4; ++r) {
      stats[0][w][lg * 4 + r] = mx[r];
      stats[1][w][lg * 4 + r] = sr[r];
      stats[2][w][lg * 4 + r] = spr[r];
    }
  }
  __syncthreads();
  float mr[4], rinv[4];
  #pragma unroll
  for (int r = 0; r < 4; ++r) {
    const int row = lg * 4 + r;
    float M = NEG_MAX, S = 0.f, SP = 0.f;
    #pragma unroll
    for (int wv = 0; wv < 4; ++wv) {
      const float m2 = stats[0][wv][row];
      const float s2 = stats[1][wv][row];
      const float sp2 = stats[2][wv][row];
      const float mn = fmaxf(M, m2);
      const float f1 = __expf(M - mn), f2 = __expf(m2 - mn);
      S = S * f1 + s2 * f2;
      SP = SP * f1 + sp2 * f2;
      M = mn;
    }
    mr[r] = M;
    rinv[r] = 1.f / fmaxf(SP, 1e-6f * S);
  }

  // ---- attn values: write global + stage bf16 P in per-wave LDS ----
  float* attn_b = attn + (size_t)bz * NSQ;
  #pragma unroll
  for (int nt = 0; nt < 6; ++nt) {
    #pragma unroll
    for (int r = 0; r < 4; ++r) {
      const int m = m0 + lg * 4 + r;
      const int n = n0 + nt * 16 + l15;
      const float e = __expf(acc[nt][r] - mr[r]);
      const float a = ((pmmask >> (nt * 4 + r)) & 1) ? e * rinv[r] : 0.f;
      attn_b[(size_t)m * Nn + n] = a;
      pstage[w][lg * 4 + r][nt * 16 + l15] = f2bfu(a);
    }
  }
  __syncthreads();

  // ---- PV: wave w covers tok in [n0, n0+96); A = P from own LDS region ----
  f32x4 pacc[4] = {};
  const ushort_t* vb0 = vbT + (size_t)(bz * 64) * Nn;
  #pragma unroll
  for (int ks = 0; ks < 3; ++ks) {
    const int ktok = ks * 32 + lg * 8;           // local tok offset
    const short8 ap = *(const short8*)&pstage[w][l15][ktok];
    #pragma unroll
    for (int nt = 0; nt < 4; ++nt) {
      const short8 bvv = *(const short8*)(vb0 +
          (size_t)(nt * 16 + l15) * Nn + n0 + ktok);
      pacc[nt] = __builtin_amdgcn_mfma_f32_16x16x32_bf16(ap, bvv, pacc[nt], 0, 0, 0);
    }
  }
  // partials -> LDS
  #pragma unroll
  for (int nt = 0; nt < 4; ++nt)
    #pragma unroll
    for (int r = 0; r < 4; ++r)
      part[w][lg * 4 + r][nt * 16 + l15] = pacc[nt][r];
  __syncthreads();
  // combine + store
  {
    const int o = tid * 4;
    const int row = o >> 6, dh0 = o & 63;
    f32x4 s = *(const f32x4*)&part[0][row][dh0];
    s += *(const f32x4*)&part[1][row][dh0];
    s += *(const f32x4*)&part[2][row][dh0];
    s += *(const f32x4*)&part[3][row][dh0];
    ushort4 st;
    st.x = f2bfu(s[0]); st.y = f2bfu(s[1]); st.z = f2bfu(s[2]); st.w = f2bfu(s[3]);
    *(ushort4*)(aoB + (size_t)(b * Nn + m0 + row) * Dd + h * 64 + dh0) = st;
  }
}

// ---------------------------------------------------------------------------
// FF1 with fused gate: agB = (xnb@ffW1[:512]^T + b_a) * gelu(xnb@ffW1[512:]^T
// + b_g), bf16 out.  grid (8, 24); block = 4 waves; wave: 16(M) x 64(N).
// ---------------------------------------------------------------------------
__global__ __launch_bounds__(256) void ffn1_kernel(
    const ushort_t* __restrict__ xnb, const ushort_t* __restrict__ ffW1B,
    const float* __restrict__ ffb1, ushort_t* __restrict__ agB)
{
  const int tid = threadIdx.x;
  const int lane = tid & 63;
  const int w   = tid >> 6;
  const int l15 = lane & 15, lg = lane >> 4;
  const int m0 = blockIdx.y * 64 + w * 16;
  const int n0 = blockIdx.x * 64;

  f32x4 accA[4] = {}, accG[4] = {};
  const ushort_t* pa = xnb + (size_t)(m0 + l15) * Dd + lg * 8;
  for (int k0 = 0; k0 < Dd; k0 += 32) {
    const short8 af = *(const short8*)(pa + k0);
    #pragma unroll
    for (int nt = 0; nt < 4; ++nt) {
      const short8 bfa = *(const short8*)(ffW1B +
          (size_t)(n0 + nt * 16 + l15) * Dd + k0 + lg * 8);
      const short8 bfg = *(const short8*)(ffW1B +
          (size_t)(512 + n0 + nt * 16 + l15) * Dd + k0 + lg * 8);
      accA[nt] = __builtin_amdgcn_mfma_f32_16x16x32_bf16(af, bfa, accA[nt], 0, 0, 0);
      accG[nt] = __builtin_amdgcn_mfma_f32_16x16x32_bf16(af, bfg, accG[nt], 0, 0, 0);
    }
  }
  #pragma unroll
  for (int nt = 0; nt < 4; ++nt) {
    #pragma unroll
    for (int r = 0; r < 4; ++r) {
      const int m = m0 + lg * 4 + r;
      const int n = n0 + nt * 16 + l15;
      const float a = accA[nt][r] + ffb1[n];
      const float g = accG[nt][r] + ffb1[512 + n];
      agB[(size_t)m * 512 + n] = f2bfu(a * gelu_f(g));
    }
  }
}

// ---------------------------------------------------------------------------
// bf16-operand MFMA GEMM (MODE 0 only): C(f32) = A16 @ B^T (+bias)(+res).
// ---------------------------------------------------------------------------
__global__ __launch_bounds__(256) void gemm2(
    const ushort_t* __restrict__ A16, int lda,
    const ushort_t* __restrict__ Bm, int ldb,
    float* __restrict__ Cc, int ldc,
    const float* __restrict__ bias,
    const float* __restrict__ res, int ldr,
    int K)
{
  const int tid = threadIdx.x;
  const int lane = tid & 63;
  const int w   = tid >> 6;
  const int l15 = lane & 15, lg = lane >> 4;
  const int m0 = blockIdx.y * 64 + w * 16;
  const int n0 = blockIdx.x * 64;

  f32x4 acc[4] = {};
  const ushort_t* pa16 = A16 + (size_t)(m0 + l15) * lda + lg * 8;
  for (int k0 = 0; k0 < K; k0 += 32) {
    const short8 af = *(const short8*)(pa16 + k0);
    #pragma unroll
    for (int nt = 0; nt < 4; ++nt) {
      const short8 bf = *(const short8*)(Bm +
          (size_t)(n0 + nt * 16 + l15) * ldb + k0 + lg * 8);
      acc[nt] = __builtin_amdgcn_mfma_f32_16x16x32_bf16(af, bf, acc[nt], 0, 0, 0);
    }
  }
  #pragma unroll
  for (int nt = 0; nt < 4; ++nt) {
    #pragma unroll
    for (int r = 0; r < 4; ++r) {
      const int m = m0 + lg * 4 + r;
      const int n = n0 + nt * 16 + l15;
      float v = acc[nt][r];
      if (bias) v += bias[n];
      if (res)  v += res[(size_t)m * ldr + n];
      Cc[(size_t)m * ldc + n] = v;
    }
  }
}

// ---------------------------------------------------------------------------
extern "C" void kernel_launch(void* const* d_in, const int* in_sizes, int n_in,
                              void* d_out, int out_size, void* d_ws, size_t ws_size,
                              hipStream_t stream) {
  const float* x    = (const float*)d_in[0];
  const int*   pm   = (const int*)  d_in[1];
  const int*   vld  = (const int*)  d_in[2];
  const float* cont = (const float*)d_in[3];
  const int* dbk = (const int*)d_in[4];
  const int* drk = (const int*)d_in[5];
  const int* rpk = (const int*)d_in[6];
  const int* hdk = (const int*)d_in[7];
  const int* etk = (const int*)d_in[8];
  const int* spk = (const int*)d_in[9];
  const int* sck = (const int*)d_in[10];
  const int* dgk = (const int*)d_in[11];
  const int* ctk = (const int*)d_in[12];
  const float* Wq  = (const float*)d_in[13];
  const float* Wk  = (const float*)d_in[14];
  const float* Wv  = (const float*)d_in[15];
  const float* Wo  = (const float*)d_in[16];
  const float* bo  = (const float*)d_in[17];
  const float* cmW1 = (const float*)d_in[18];
  const float* cmb1 = (const float*)d_in[19];
  const float* cmW2 = (const float*)d_in[20];
  const float* cmb2 = (const float*)d_in[21];
  const float* Ed  = (const float*)d_in[22];
  const float* Edi = (const float*)d_in[23];
  const float* Er  = (const float*)d_in[24];
  const float* Eh  = (const float*)d_in[25];
  const float* Ee  = (const float*)d_in[26];
  const float* Esp = (const float*)d_in[27];
  const float* Edg = (const float*)d_in[28];
  const float* Ec  = (const float*)d_in[29];
  const float* Es  = (const float*)d_in[30];
  const float* blng = (const float*)d_in[31];
  const float* blnb = (const float*)d_in[32];
  const float* bW   = (const float*)d_in[33];
  const float* bb_  = (const float*)d_in[34];
  const float* ln1g = (const float*)d_in[35];
  const float* ln1b = (const float*)d_in[36];
  const float* ln2g = (const float*)d_in[37];
  const float* ln2b = (const float*)d_in[38];
  const float* ffW1 = (const float*)d_in[39];
  const float* ffb1 = (const float*)d_in[40];
  const float* ffW2 = (const float*)d_in[41];
  const float* ffb2 = (const float*)d_in[42];

  float* out   = (float*)d_out;
  float* xout  = out;                       // 393216
  float* attn  = out + 393216;              // 2359296
  float* biasO = out + 393216 + 2359296;    // 2359296

  float* ws = (float*)d_ws;
  // persistent bf16 weights [0, 327680)
  ushort_t* wqB   = (ushort_t*)(ws);             // 65536 ush
  ushort_t* wkB   = (ushort_t*)(ws + 32768);
  ushort_t* wvB   = (ushort_t*)(ws + 65536);
  ushort_t* woB   = (ushort_t*)(ws + 98304);
  ushort_t* ffW1B = (ushort_t*)(ws + 131072);    // 262144 ush
  ushort_t* ffW2B = (ushort_t*)(ws + 262144);    // 131072 ush
  // epoch 1 (pair path; dead after pair_kernel) [327680, 2794304)
  ushort_t* contP = (ushort_t*)(ws + 327680);    // 4718592 ush
  ushort_t* dcP   = (ushort_t*)(ws + 2686976);   // 98304 ush
  ushort_t* dcbP  = (ushort_t*)(ws + 2736128);   // 98304 ush
  ushort_t* EddP  = (ushort_t*)(ws + 2785280);   // 5760 ush
  ushort_t* ErsP  = (ushort_t*)(ws + 2788160);   // 3840 ush
  ushort_t* EhesP = (ushort_t*)(ws + 2790080);   // 3840 ush
  ushort_t* w1bf  = (ushort_t*)(ws + 2792000);   // 512 ush
  ushort_t* w2bf  = (ushort_t*)(ws + 2792256);   // 4096 ush
  // epoch 2 (attention/FFN; lives after pair) [327680, 3276800)
  ushort_t* xnb = (ushort_t*)(ws + 327680);      // 393216 ush
  ushort_t* qbB = (ushort_t*)(ws + 524288);
  ushort_t* kbB = (ushort_t*)(ws + 720896);
  ushort_t* vbT = (ushort_t*)(ws + 917504);
  ushort_t* aoB = (ushort_t*)(ws + 1114112);
  float* x1  = ws + 1310720;                     // 393216 f32
  ushort_t* agB = (ushort_t*)(ws + 1703936);     // 786432 ush

  // 0) prep + pack (merged)
  prep_kernel<<<3062, 256, 0, stream>>>(dgk, ctk, Edg, Ec, cmb2, cmW1, cmb1,
      cmW2, Ed, Edi, Er, Eh, Ee, Esp, Es, Wq, Wk, Wv, Wo, ffW1, ffW2,
      dbk, drk, rpk, hdk, etk, spk, sck, pm, cont,
      dcP, dcbP, w1bf, w2bf, EddP, ErsP, EhesP,
      wqB, wkB, wvB, woB, ffW1B, ffW2B, contP);
  // 1) pair bias (MFMA, 3 tiles/wave, 3 waves/SIMD -- measured optimum)
  pair_kernel<<<3072, 256, 0, stream>>>(contP, w1bf, w2bf, EddP, ErsP, EhesP,
      blng, blnb, bW, bb_, dcP, dcbP, biasO);
  // 2) ln1 -> xnb (bf16)
  ln_kernel<<<384, 256, 0, stream>>>(x, ln1g, ln1b, xnb);
  // 3) q, k, V^T projections (all-bf16)
  qkv_kernel<<<dim3(4, 24, 3), 256, 0, stream>>>(xnb, wqB, wkB, wvB,
      qbB, kbB, vbT);
  // 4) fused attention: QK^T + softmax + attn write + PV -> aoB
  attn_kernel<<<dim3(24, 16), 256, 0, stream>>>(qbB, kbB, vbT, biasO, pm, vld,
      attn, aoB);
  // 5) Wo + bo + residual(x) -> x1
  gemm2<<<dim3(4, 24), 256, 0, stream>>>(aoB, 256, woB, 256,
      x1, 256, bo, x, 256, 256);
  // 6) ln2 -> xnb
  ln_kernel<<<384, 256, 0, stream>>>(x1, ln2g, ln2b, xnb);
  // 7) FF1 with fused gate -> agB (bf16)
  ffn1_kernel<<<dim3(8, 24), 256, 0, stream>>>(xnb, ffW1B, ffb1, agB);
  // 8) FF2 + ffb2 + residual(x1) -> x_out
  gemm2<<<dim3(4, 24), 256, 0, stream>>>(agB, 512, ffW2B, 512,
      xout, 256, ffb2, x1, 256, 512);
}